// Round 18
// baseline (347.326 us; speedup 1.0000x reference)
//
#include <hip/hip_runtime.h>
#include <hip/hip_bf16.h>
#include <math.h>

#define SS 1024
#define BB 4
#define DD 1024
#define HH 16
#define FFF 4096
#define MM (SS*BB)   // 4096 token rows

typedef __attribute__((ext_vector_type(8))) short bf16x8;
typedef __attribute__((ext_vector_type(4))) float f32x4;

#define VM_WAIT(n) asm volatile("s_waitcnt vmcnt(" #n ")" ::: "memory")
#define MEM_FENCE() asm volatile("" ::: "memory")

// ---------------- RMSNorm: one block (256 thr) per row, bf16 out ----------------
__global__ void rmsnorm_kernel(const float* __restrict__ x, const float* __restrict__ g,
                               __hip_bfloat16* __restrict__ out) {
    int row = blockIdx.x;
    const float* xr = x + (size_t)row * DD;
    int tid = threadIdx.x;
    float4 v = *reinterpret_cast<const float4*>(xr + tid * 4);
    float ss = v.x*v.x + v.y*v.y + v.z*v.z + v.w*v.w;
    #pragma unroll
    for (int off = 32; off; off >>= 1) ss += __shfl_down(ss, off);
    __shared__ float part[4];
    if ((tid & 63) == 0) part[tid >> 6] = ss;
    __syncthreads();
    float tot = part[0] + part[1] + part[2] + part[3];
    float rms = sqrtf(tot) * (1.0f / 32.0f);
    float inv = 1.0f / (rms + 1e-8f);
    float4 gv = *reinterpret_cast<const float4*>(g + tid * 4);
    union { __hip_bfloat16 h[4]; uint2 u; } p;
    p.h[0] = __float2bfloat16(gv.x * v.x * inv);
    p.h[1] = __float2bfloat16(gv.y * v.y * inv);
    p.h[2] = __float2bfloat16(gv.z * v.z * inv);
    p.h[3] = __float2bfloat16(gv.w * v.w * inv);
    reinterpret_cast<uint2*>(out + (size_t)row * DD)[tid] = p.u;
}

// ---------------- fp32 -> bf16 elementwise ----------------
__global__ void f2b_kernel(const float* __restrict__ in, __hip_bfloat16* __restrict__ out) {
    int i = blockIdx.x * 256 + threadIdx.x;
    float4 v = reinterpret_cast<const float4*>(in)[i];
    union { __hip_bfloat16 h[4]; uint2 u; } p;
    p.h[0] = __float2bfloat16(v.x);
    p.h[1] = __float2bfloat16(v.y);
    p.h[2] = __float2bfloat16(v.z);
    p.h[3] = __float2bfloat16(v.w);
    reinterpret_cast<uint2*>(out)[i] = p.u;
}

// ---------------- bias concat (2 or 3 segments of n floats) ----------------
__global__ void bias_concat(const float* __restrict__ a, const float* __restrict__ b,
                            const float* __restrict__ c, float* __restrict__ o, int n) {
    int total = (c ? 3 : 2) * n;
    int i = blockIdx.x * 256 + threadIdx.x;
    if (i >= total) return;
    int seg = i / n, off = i - seg * n;
    const float* p = seg == 0 ? a : (seg == 1 ? b : c);
    o[i] = p[off];
}

// ---------------- batched transpose-convert: 8x W[1024,1024] fp32 -> Wt bf16 ----------------
__global__ void wtrans8_kernel(const float* s0, const float* s1, const float* s2, const float* s3,
                               const float* s4, const float* s5, const float* s6, const float* s7,
                               __hip_bfloat16* d0, __hip_bfloat16* d1, __hip_bfloat16* d2,
                               __hip_bfloat16* d3, __hip_bfloat16* d4, __hip_bfloat16* d5,
                               __hip_bfloat16* d6, __hip_bfloat16* d7) {
    const float* W; __hip_bfloat16* Wt;
    switch (blockIdx.z) {
        case 0: W = s0; Wt = d0; break;
        case 1: W = s1; Wt = d1; break;
        case 2: W = s2; Wt = d2; break;
        case 3: W = s3; Wt = d3; break;
        case 4: W = s4; Wt = d4; break;
        case 5: W = s5; Wt = d5; break;
        case 6: W = s6; Wt = d6; break;
        default: W = s7; Wt = d7; break;
    }
    __shared__ float tile[32][33];
    int n0 = blockIdx.x * 32, k0 = blockIdx.y * 32;
    int tx = threadIdx.x & 31, ty = threadIdx.x >> 5;
    #pragma unroll
    for (int i = 0; i < 4; i++) {
        int kk = ty + i * 8;
        tile[kk][tx] = W[(size_t)(k0 + kk) * DD + n0 + tx];
    }
    __syncthreads();
    #pragma unroll
    for (int i = 0; i < 4; i++) {
        int nn = ty + i * 8;
        Wt[(size_t)(n0 + nn) * DD + k0 + tx] = __float2bfloat16(tile[tx][nn]);
    }
}

// ---------------- transpose-convert: W[K,N] fp32 -> Wt[N,K] bf16 ----------------
__global__ void wtrans_kernel(const float* __restrict__ W, __hip_bfloat16* __restrict__ Wt,
                              int K, int N) {
    __shared__ float tile[32][33];
    int n0 = blockIdx.x * 32, k0 = blockIdx.y * 32;
    int tx = threadIdx.x & 31, ty = threadIdx.x >> 5;
    #pragma unroll
    for (int i = 0; i < 4; i++) {
        int kk = ty + i * 8;
        tile[kk][tx] = W[(size_t)(k0 + kk) * N + n0 + tx];
    }
    __syncthreads();
    #pragma unroll
    for (int i = 0; i < 4; i++) {
        int nn = ty + i * 8;
        Wt[(size_t)(n0 + nn) * K + k0 + tx] = __float2bfloat16(tile[tx][nn]);
    }
}

// ---------------- bf16 MFMA GEMM (proven r10 kernel) ----------------
// EPI: 0 = bias -> bf16 ; 1 = bias+silu -> bf16 ; 2 = bias+residual -> fp32
template<int EPI, int BM, int BN>
__global__ __launch_bounds__(256) void gemm_bf16(
    const __hip_bfloat16* __restrict__ A, const __hip_bfloat16* __restrict__ Bt,
    const float* __restrict__ bias, const float* __restrict__ res,
    float* __restrict__ Cf, __hip_bfloat16* __restrict__ Cb, int K, int N)
{
    constexpr int MFRAG = BM / 32;
    constexpr int NFRAG = BN / 32;
    constexpr int WM = BM / 2, WN = BN / 2;
    constexpr int LPT = (BM + BN) / 32;
    __shared__ __hip_bfloat16 As[2][BM * 64];
    __shared__ __hip_bfloat16 Bs[2][BN * 64];
    int tid = threadIdx.x;
    int lane = tid & 63, w = tid >> 6;
    int wr = w >> 1, wc = w & 1;

    int gx = gridDim.x;
    int nwg = gx * gridDim.y;
    int orig = blockIdx.y * gx + blockIdx.x;
    int qd = nwg >> 3, rr2 = nwg & 7, xcd = orig & 7, pos = orig >> 3;
    int lin = (xcd < rr2 ? xcd * (qd + 1) : rr2 * (qd + 1) + (xcd - rr2) * qd) + pos;
    int brow = (lin / gx) * BM, bcol = (lin % gx) * BN;

    f32x4 acc[MFRAG][NFRAG];
    #pragma unroll
    for (int m = 0; m < MFRAG; m++)
        #pragma unroll
        for (int n = 0; n < NFRAG; n++)
            acc[m][n] = (f32x4){0.f, 0.f, 0.f, 0.f};

    const __hip_bfloat16* Ab = A + (size_t)brow * K;
    const __hip_bfloat16* Bb = Bt + (size_t)bcol * K;

    auto stage = [&](int buf, int kt) {
        #pragma unroll
        for (int i = 0; i < BM / 32; i++) {
            int f = i * 256 + tid;
            int row = f >> 3, cp = f & 7;
            int cs = cp ^ (row & 7);
            __builtin_amdgcn_global_load_lds(
                (const __attribute__((address_space(1))) void*)(Ab + (size_t)row * K + kt + cs * 8),
                (__attribute__((address_space(3))) void*)(As[buf] + (size_t)(i * 256 + w * 64) * 8),
                16, 0, 0);
        }
        #pragma unroll
        for (int i = 0; i < BN / 32; i++) {
            int f = i * 256 + tid;
            int row = f >> 3, cp = f & 7;
            int cs = cp ^ (row & 7);
            __builtin_amdgcn_global_load_lds(
                (const __attribute__((address_space(1))) void*)(Bb + (size_t)row * K + kt + cs * 8),
                (__attribute__((address_space(3))) void*)(Bs[buf] + (size_t)(i * 256 + w * 64) * 8),
                16, 0, 0);
        }
    };

    int nt = K >> 6;
    stage(0, 0);
    if (nt > 1) stage(1, 64);

    int cb = 0;
    int r = lane & 15, g = lane >> 4;
    for (int t = 0; t < nt; t++) {
        if (t + 1 < nt) {
            if constexpr (LPT == 4) VM_WAIT(4); else VM_WAIT(8);
        } else VM_WAIT(0);
        __builtin_amdgcn_s_barrier();
        MEM_FENCE();

        bf16x8 aF[2][MFRAG], bF[2][NFRAG];
        #pragma unroll
        for (int kk = 0; kk < 2; kk++) {
            #pragma unroll
            for (int m = 0; m < MFRAG; m++) {
                int row = WM * wr + m * 16 + r;
                aF[kk][m] = *reinterpret_cast<const bf16x8*>(
                    As[cb] + (size_t)row * 64 + (size_t)((kk * 4 + g) ^ (row & 7)) * 8);
            }
            #pragma unroll
            for (int n = 0; n < NFRAG; n++) {
                int row = WN * wc + n * 16 + r;
                bF[kk][n] = *reinterpret_cast<const bf16x8*>(
                    Bs[cb] + (size_t)row * 64 + (size_t)((kk * 4 + g) ^ (row & 7)) * 8);
            }
        }
        __builtin_amdgcn_s_setprio(1);
        #pragma unroll
        for (int kk = 0; kk < 2; kk++)
            #pragma unroll
            for (int m = 0; m < MFRAG; m++)
                #pragma unroll
                for (int n = 0; n < NFRAG; n++)
                    acc[m][n] = __builtin_amdgcn_mfma_f32_16x16x32_bf16(aF[kk][m], bF[kk][n], acc[m][n], 0, 0, 0);
        __builtin_amdgcn_s_setprio(0);

        MEM_FENCE();
        __builtin_amdgcn_s_barrier();
        if (t + 2 < nt) stage(cb, (t + 2) << 6);
        cb ^= 1;
    }

    int row0 = brow + WM * wr + (g * 4);
    int col0 = bcol + WN * wc + r;
    #pragma unroll
    for (int m = 0; m < MFRAG; m++) {
        #pragma unroll
        for (int n = 0; n < NFRAG; n++) {
            int ccol = col0 + n * 16;
            float bv = bias[ccol];
            #pragma unroll
            for (int q = 0; q < 4; q++) {
                int rrow = row0 + m * 16 + q;
                float o = acc[m][n][q] + bv;
                if (EPI == 0) {
                    Cb[(size_t)rrow * N + ccol] = __float2bfloat16(o);
                } else if (EPI == 1) {
                    o = o / (1.0f + __expf(-o));
                    Cb[(size_t)rrow * N + ccol] = __float2bfloat16(o);
                } else {
                    o += res[(size_t)rrow * N + ccol];
                    Cf[(size_t)rrow * N + ccol] = o;
                }
            }
        }
    }
}

// ---------------- 8-wave 256x256 GEMM: BK=64, waves 2(M)x4(N), per-wave 128x64 ----------------
// GEOMETRY (fixed from r16 bug): M = 2 waves x 128 = 256 = BM; N = 4 waves x 64 = 256 = BN.
// Per K-tile/wave: 24 ds_read_b128 (~288cy) vs 64 MFMA (~310cy) -> MFMA-bound.
// LDS 128KB (As 64KB + Bs 64KB) -> 1 block/CU, 8 waves = 2/SIMD.
// Proven row&7 chunk swizzle (128B rows); T4 counted vmcnt (LPT=8); T5 setprio.
// Used ONLY where grid >= 256 blocks (FFN-up: 16x16 = 256). EPI 1 = bias+silu.
template<int EPI>
__global__ __launch_bounds__(512) void gemm8w_bf16(
    const __hip_bfloat16* __restrict__ A, const __hip_bfloat16* __restrict__ Bt,
    const float* __restrict__ bias, __hip_bfloat16* __restrict__ Cb, int K, int N)
{
    constexpr int BM = 256, BN = 256;
    constexpr int MFRAG = 8, NFRAG = 4;        // per-wave 128 x 64
    __shared__ __hip_bfloat16 As[2][BM * 64];  // 64 KB
    __shared__ __hip_bfloat16 Bs[2][BN * 64];  // 64 KB
    int tid = threadIdx.x;
    int lane = tid & 63, w = tid >> 6;         // w 0..7
    int wr = w >> 2, wc = w & 3;               // 2 x 4

    // bijective XCD-chunked swizzle (m204)
    int gx = gridDim.x;
    int nwg = gx * gridDim.y;
    int orig = blockIdx.y * gx + blockIdx.x;
    int qd = nwg >> 3, rr2 = nwg & 7, xcd = orig & 7, pos = orig >> 3;
    int lin = (xcd < rr2 ? xcd * (qd + 1) : rr2 * (qd + 1) + (xcd - rr2) * qd) + pos;
    int brow = (lin / gx) * BM, bcol = (lin % gx) * BN;

    f32x4 acc[MFRAG][NFRAG];
    #pragma unroll
    for (int m = 0; m < MFRAG; m++)
        #pragma unroll
        for (int n = 0; n < NFRAG; n++)
            acc[m][n] = (f32x4){0.f, 0.f, 0.f, 0.f};

    const __hip_bfloat16* Ab = A + (size_t)brow * K;
    const __hip_bfloat16* Bb = Bt + (size_t)bcol * K;

    // A: 256 rows x 8 chunks = 2048 chunks / 512 thr = 4 iters; B identical.
    auto stage = [&](int buf, int kt) {
        #pragma unroll
        for (int i = 0; i < 4; i++) {
            int f = i * 512 + tid;
            int row = f >> 3, cp = f & 7;
            int cs = cp ^ (row & 7);
            __builtin_amdgcn_global_load_lds(
                (const __attribute__((address_space(1))) void*)(Ab + (size_t)row * K + kt + cs * 8),
                (__attribute__((address_space(3))) void*)(As[buf] + (size_t)(i * 512 + w * 64) * 8),
                16, 0, 0);
        }
        #pragma unroll
        for (int i = 0; i < 4; i++) {
            int f = i * 512 + tid;
            int row = f >> 3, cp = f & 7;
            int cs = cp ^ (row & 7);
            __builtin_amdgcn_global_load_lds(
                (const __attribute__((address_space(1))) void*)(Bb + (size_t)row * K + kt + cs * 8),
                (__attribute__((address_space(3))) void*)(Bs[buf] + (size_t)(i * 512 + w * 64) * 8),
                16, 0, 0);
        }
    };

    int nt = K >> 6;
    stage(0, 0);
    if (nt > 1) stage(1, 64);

    int cb = 0;
    int r = lane & 15, g = lane >> 4;
    for (int t = 0; t < nt; t++) {
        if (t + 1 < nt) VM_WAIT(8); else VM_WAIT(0);   // next tile's 8 loads stay in flight
        __builtin_amdgcn_s_barrier();
        MEM_FENCE();

        #pragma unroll
        for (int kk = 0; kk < 2; kk++) {               // kk-scoped frags cap VGPR
            bf16x8 aF[MFRAG], bF[NFRAG];
            #pragma unroll
            for (int m = 0; m < MFRAG; m++) {
                int row = 128 * wr + m * 16 + r;       // 0..255 within As
                aF[m] = *reinterpret_cast<const bf16x8*>(
                    As[cb] + (size_t)row * 64 + (size_t)((kk * 4 + g) ^ (row & 7)) * 8);
            }
            #pragma unroll
            for (int n = 0; n < NFRAG; n++) {
                int row = 64 * wc + n * 16 + r;        // 0..255 within Bs
                bF[n] = *reinterpret_cast<const bf16x8*>(
                    Bs[cb] + (size_t)row * 64 + (size_t)((kk * 4 + g) ^ (row & 7)) * 8);
            }
            __builtin_amdgcn_s_setprio(1);
            #pragma unroll
            for (int m = 0; m < MFRAG; m++)
                #pragma unroll
                for (int n = 0; n < NFRAG; n++)
                    acc[m][n] = __builtin_amdgcn_mfma_f32_16x16x32_bf16(aF[m], bF[n], acc[m][n], 0, 0, 0);
            __builtin_amdgcn_s_setprio(0);
        }

        MEM_FENCE();
        __builtin_amdgcn_s_barrier();
        if (t + 2 < nt) stage(cb, (t + 2) << 6);
        cb ^= 1;
    }

    int row0 = brow + 128 * wr + (g * 4);
    int col0 = bcol + 64 * wc + r;
    #pragma unroll
    for (int m = 0; m < MFRAG; m++) {
        #pragma unroll
        for (int n = 0; n < NFRAG; n++) {
            int ccol = col0 + n * 16;
            float bv = bias[ccol];
            #pragma unroll
            for (int q = 0; q < 4; q++) {
                int rrow = row0 + m * 16 + q;
                float o = acc[m][n][q] + bv;
                if (EPI == 1) o = o / (1.0f + __expf(-o));
                Cb[(size_t)rrow * N + ccol] = __float2bfloat16(o);
            }
        }
    }
}

// ---------------- fused Q/K RoPE + relayout + V transpose (unchanged, passing) ----------------
__global__ __launch_bounds__(256) void qkv_prep(
    const __hip_bfloat16* __restrict__ Q, int qs,
    const __hip_bfloat16* __restrict__ K, int ks2,
    const __hip_bfloat16* __restrict__ V, int vs,
    __hip_bfloat16* __restrict__ Qh, __hip_bfloat16* __restrict__ Kh,
    __hip_bfloat16* __restrict__ Vt, float qscale)
{
    int tid = threadIdx.x;
    int bh = blockIdx.y;
    int b = bh >> 4, h = bh & 15;
    int s0 = blockIdx.x * 64;
    #pragma unroll
    for (int sel = 0; sel < 2; sel++) {
        const __hip_bfloat16* src = sel ? K : Q;
        int stride = sel ? ks2 : qs;
        __hip_bfloat16* dst = sel ? Kh : Qh;
        float sc = sel ? 1.0f : qscale;
        #pragma unroll
        for (int it = 0; it < 2; it++) {
            int f = it * 256 + tid;
            int i = f >> 3, c8 = f & 7;
            int s = s0 + i;
            union { uint4 u; __hip_bfloat16 hh[8]; } d;
            d.u = *reinterpret_cast<const uint4*>(src + (size_t)(s * BB + b) * stride + h * 64 + c8 * 8);
            float fv[8];
            #pragma unroll
            for (int e = 0; e < 8; e++) fv[e] = __bfloat162float(d.hh[e]);
            if (c8 < 4) {
                #pragma unroll
                for (int pp = 0; pp < 4; pp++) {
                    int p = c8 * 4 + pp;
                    float ang = (float)s * __powf(10000.f, -(float)p * (1.0f / 16.0f));
                    float cc, sn;
                    __sincosf(ang, &sn, &cc);
                    float x0 = fv[pp * 2], x1 = fv[pp * 2 + 1];
                    fv[pp * 2]     = x0 * cc - x1 * sn;
                    fv[pp * 2 + 1] = x1 * cc + x0 * sn;
                }
            }
            #pragma unroll
            for (int e = 0; e < 8; e++) d.hh[e] = __float2bfloat16(fv[e] * sc);
            *reinterpret_cast<uint4*>(dst + ((size_t)bh * SS + s) * 64 + c8 * 8) = d.u;
        }
    }
    __shared__ __hip_bfloat16 t[64][72];
    #pragma unroll
    for (int i = 0; i < 2; i++) {
        int f = tid + i * 256;
        int sr = f >> 3, c = (f & 7) * 8;
        *reinterpret_cast<uint4*>(&t[sr][c]) =
            *reinterpret_cast<const uint4*>(V + (size_t)((s0 + sr) * BB + b) * vs + h * 64 + c);
    }
    __syncthreads();
    #pragma unroll
    for (int i = 0; i < 2; i++) {
        int f = tid + i * 256;
        int d = f >> 3, c = (f & 7) * 8;
        __hip_bfloat16 tmp[8];
        #pragma unroll
        for (int j = 0; j < 8; j++) tmp[j] = t[c + j][d];
        *reinterpret_cast<uint4*>(Vt + ((size_t)bh * 64 + d) * SS + s0 + c) =
            *reinterpret_cast<uint4*>(tmp);
    }
}

// ---------------- MFMA flash attention (unchanged from r15, passing) ----------------
template<bool CAUSAL>
__global__ __launch_bounds__(512) void attn_mfma(
    const __hip_bfloat16* __restrict__ Qh, const __hip_bfloat16* __restrict__ Kh,
    const __hip_bfloat16* __restrict__ Vth, __hip_bfloat16* __restrict__ O)
{
    __shared__ __hip_bfloat16 Ks[2][64 * 64];
    __shared__ __hip_bfloat16 Vs[2][64 * 64];
    __shared__ __hip_bfloat16 Ps[8][16][72];
    int tid = threadIdx.x, lane = tid & 63, w = tid >> 6;
    int r = lane & 15, g = lane >> 4;

    int lin = blockIdx.y * gridDim.x + blockIdx.x;
    int bh = (lin & 7) * 8 + ((lin >> 3) & 7);
    int qblk = lin >> 6;
    int b = bh >> 4, h = bh & 15;
    int qb = qblk * 128;
    const __hip_bfloat16* gQ = Qh + (size_t)bh * SS * 64;
    const __hip_bfloat16* gK = Kh + (size_t)bh * SS * 64;
    const __hip_bfloat16* gV = Vth + (size_t)bh * 64 * SS;

    bf16x8 qf0 = *reinterpret_cast<const bf16x8*>(gQ + (size_t)(qb + w * 16 + r) * 64 + g * 8);
    bf16x8 qf1 = *reinterpret_cast<const bf16x8*>(gQ + (size_t)(qb + w * 16 + r) * 64 + 32 + g * 8);

    const short oneb = (short)0x3F80;
    bf16x8 onesV = {oneb, oneb, oneb, oneb, oneb, oneb, oneb, oneb};

    f32x4 accO[4];
    f32x4 accL = (f32x4){0.f, 0.f, 0.f, 0.f};
    #pragma unroll
    for (int j = 0; j < 4; j++) accO[j] = (f32x4){0.f, 0.f, 0.f, 0.f};

    int nt = CAUSAL ? 2 * (qblk + 1) : (SS / 64);

    auto stage = [&](int buf, int kt) {
        int row = tid >> 3, cp = tid & 7;
        int cs = cp ^ (row & 7);
        __builtin_amdgcn_global_load_lds(
            (const __attribute__((address_space(1))) void*)(gK + (size_t)(kt + row) * 64 + cs * 8),
            (__attribute__((address_space(3))) void*)(&Ks[buf][(size_t)tid * 8]),
            16, 0, 0);
        __builtin_amdgcn_global_load_lds(
            (const __attribute__((address_space(1))) void*)(gV + (size_t)row * SS + kt + cs * 8),
            (__attribute__((address_space(3))) void*)(&Vs[buf][(size_t)tid * 8]),
            16, 0, 0);
    };

    stage(0, 0);
    if (nt > 1) stage(1, 64);
    int cb = 0;
    for (int t = 0; t < nt; t++) {
        if (t + 1 < nt) VM_WAIT(2); else VM_WAIT(0);
        __builtin_amdgcn_s_barrier();
        MEM_FENCE();
        int kt = t * 64;

        f32x4 sa[4];
        __builtin_amdgcn_s_setprio(1);
        #pragma unroll
        for (int ks = 0; ks < 4; ks++) {
            sa[ks] = (f32x4){0.f, 0.f, 0.f, 0.f};
            int rk = ks * 16 + r;
            bf16x8 kf0 = *reinterpret_cast<const bf16x8*>(&Ks[cb][rk * 64 + ((g ^ (rk & 7)) * 8)]);
            bf16x8 kf1 = *reinterpret_cast<const bf16x8*>(&Ks[cb][rk * 64 + (((4 + g) ^ (rk & 7)) * 8)]);
            sa[ks] = __builtin_amdgcn_mfma_f32_16x16x32_bf16(qf0, kf0, sa[ks], 0, 0, 0);
            sa[ks] = __builtin_amdgcn_mfma_f32_16x16x32_bf16(qf1, kf1, sa[ks], 0, 0, 0);
        }
        __builtin_amdgcn_s_setprio(0);

        if (CAUSAL && t >= nt - 2) {
            #pragma unroll
            for (int ks = 0; ks < 4; ks++) {
                int key = kt + ks * 16 + r;
                #pragma unroll
                for (int j = 0; j < 4; j++) {
                    int qq = qb + w * 16 + g * 4 + j;
                    if (key > qq) sa[ks][j] = -1e9f;
                }
            }
        }

        #pragma unroll
        for (int ks = 0; ks < 4; ks++)
            #pragma unroll
            for (int j = 0; j < 4; j++)
                Ps[w][g * 4 + j][ks * 16 + r] = __float2bfloat16(exp2f(sa[ks][j]));

        __builtin_amdgcn_s_setprio(1);
        #pragma unroll
        for (int ks2 = 0; ks2 < 2; ks2++) {
            bf16x8 pf = *reinterpret_cast<const bf16x8*>(&Ps[w][r][ks2 * 32 + g * 8]);
            accL = __builtin_amdgcn_mfma_f32_16x16x32_bf16(pf, onesV, accL, 0, 0, 0);
            #pragma unroll
            for (int ds = 0; ds < 4; ds++) {
                int rv = ds * 16 + r;
                bf16x8 vf = *reinterpret_cast<const bf16x8*>(
                    &Vs[cb][rv * 64 + (((ks2 * 4 + g) ^ (rv & 7)) * 8)]);
                accO[ds] = __builtin_amdgcn_mfma_f32_16x16x32_bf16(pf, vf, accO[ds], 0, 0, 0);
            }
        }
        __builtin_amdgcn_s_setprio(0);

        MEM_FENCE();
        __builtin_amdgcn_s_barrier();
        if (t + 2 < nt) stage(cb, (t + 2) * 64);
        cb ^= 1;
    }

    #pragma unroll
    for (int j = 0; j < 4; j++) {
        float inv = 1.0f / accL[j];
        int s = qb + w * 16 + g * 4 + j;
        #pragma unroll
        for (int ds = 0; ds < 4; ds++)
            O[(size_t)(s * BB + b) * DD + h * 64 + ds * 16 + r] =
                __float2bfloat16(accO[ds][j] * inv);
    }
}

extern "C" void kernel_launch(void* const* d_in, const int* in_sizes, int n_in,
                              void* d_out, int out_size, void* d_ws, size_t ws_size,
                              hipStream_t stream) {
    const float* x    = (const float*)d_in[0];
    const float* enc  = (const float*)d_in[1];
    const float* sa_wq = (const float*)d_in[3];
    const float* sa_bq = (const float*)d_in[4];
    const float* sa_wk = (const float*)d_in[5];
    const float* sa_bk = (const float*)d_in[6];
    const float* sa_wv = (const float*)d_in[7];
    const float* sa_bv = (const float*)d_in[8];
    const float* sa_wo = (const float*)d_in[9];
    const float* sa_bo = (const float*)d_in[10];
    const float* ca_wq = (const float*)d_in[11];
    const float* ca_bq = (const float*)d_in[12];
    const float* ca_wk = (const float*)d_in[13];
    const float* ca_bk = (const float*)d_in[14];
    const float* ca_wv = (const float*)d_in[15];
    const float* ca_bv = (const float*)d_in[16];
    const float* ca_wo = (const float*)d_in[17];
    const float* ca_bo = (const float*)d_in[18];
    const float* ff_w1 = (const float*)d_in[19];
    const float* ff_b1 = (const float*)d_in[20];
    const float* ff_w2 = (const float*)d_in[21];
    const float* ff_b2 = (const float*)d_in[22];
    const float* g1 = (const float*)d_in[23];
    const float* g2 = (const float*)d_in[24];
    const float* g3 = (const float*)d_in[25];
    float* out = (float*)d_out;

    // ---- workspace map (112 MB) ----
    const size_t MB = 1024 * 1024;
    char* base = (char*)d_ws;
    __hip_bfloat16* sa_qkvT = (__hip_bfloat16*)(base + 0 * MB);   // [3072][1024] 6MB
    __hip_bfloat16* sa_woT  = (__hip_bfloat16*)(base + 6 * MB);   // 2MB
    __hip_bfloat16* ca_wqT  = (__hip_bfloat16*)(base + 8 * MB);   // 2MB
    __hip_bfloat16* ca_kvT  = (__hip_bfloat16*)(base + 10 * MB);  // [2048][1024] 4MB
    __hip_bfloat16* ca_woT  = (__hip_bfloat16*)(base + 14 * MB);  // 2MB
    __hip_bfloat16* w1T     = (__hip_bfloat16*)(base + 16 * MB);  // [FFF][DD] 8MB
    __hip_bfloat16* w2T     = (__hip_bfloat16*)(base + 24 * MB);  // [DD][FFF] 8MB
    float* sa_bqkv = (float*)(base + 32 * MB);                    // 3072 f
    float* ca_bkv  = (float*)(base + 32 * MB + 16384);            // 2048 f
    __hip_bfloat16* xnb   = (__hip_bfloat16*)(base + 33 * MB);    // 8MB (also attnb)
    __hip_bfloat16* qkv   = (__hip_bfloat16*)(base + 41 * MB);    // [M][3072] 24MB
    __hip_bfloat16* Qhp   = (__hip_bfloat16*)(base + 65 * MB);    // 8MB (also encb)
    __hip_bfloat16* Khp   = (__hip_bfloat16*)(base + 73 * MB);    // 8MB
    __hip_bfloat16* Vtp   = (__hip_bfloat16*)(base + 81 * MB);    // 8MB
    float* x1 = (float*)(base + 96 * MB);                         // 16MB -> 112
    __hip_bfloat16* attnb = xnb;
    __hip_bfloat16* encb  = Qhp;
    __hip_bfloat16* qn    = qkv;                                  // CA: [M][1024] 8MB
    __hip_bfloat16* kvb   = qkv + (size_t)4 * MB;                 // CA: [M][2048] 16MB
    __hip_bfloat16* hb    = qkv;                                  // FFN: [M][FFF] 32MB (41..73)

    const float QSCALE = 0.125f * 1.44269504089f;  // 1/sqrt(64) * log2(e)

    dim3 blk(256);
    dim3 blk512(512);
    dim3 gT8(32, 32, 8);
    dim3 gW1(FFF / 32, DD / 32);
    dim3 gW2(DD / 32, FFF / 32);
    dim3 gQKV(3072 / 128, MM / 128);    // 768 blocks (proven 128^2)
    dim3 gKV(2048 / 128, MM / 128);     // 512 blocks (proven 128^2)
    dim3 gF1(FFF / 256, MM / 256);      // 16 x 16 = 256 blocks (8-wave 256^2)
    dim3 g64(DD / 64, MM / 64);         // 1024 blocks
    dim3 gPrep(SS / 64, BB * HH);
    dim3 gAtt(SS / 128, BB * HH);       // 512 blocks, 512 thr each

    // ---- one-time conversions ----
    wtrans8_kernel<<<gT8, blk, 0, stream>>>(
        sa_wq, sa_wk, sa_wv, sa_wo, ca_wq, ca_wk, ca_wv, ca_wo,
        sa_qkvT, sa_qkvT + (size_t)1024 * DD, sa_qkvT + (size_t)2048 * DD, sa_woT,
        ca_wqT, ca_kvT, ca_kvT + (size_t)1024 * DD, ca_woT);
    wtrans_kernel<<<gW1, blk, 0, stream>>>(ff_w1, w1T, DD, FFF);
    wtrans_kernel<<<gW2, blk, 0, stream>>>(ff_w2, w2T, FFF, DD);
    bias_concat<<<12, blk, 0, stream>>>(sa_bq, sa_bk, sa_bv, sa_bqkv, DD);
    bias_concat<<<8, blk, 0, stream>>>(ca_bk, ca_bv, nullptr, ca_bkv, DD);

    // ---- self-attention block ----
    rmsnorm_kernel<<<MM, blk, 0, stream>>>(x, g1, xnb);
    gemm_bf16<0, 128, 128><<<gQKV, blk, 0, stream>>>(xnb, sa_qkvT, sa_bqkv, nullptr, nullptr, qkv, DD, 3072);
    qkv_prep<<<gPrep, blk, 0, stream>>>(qkv, 3072, qkv + 1024, 3072, qkv + 2048, 3072,
                                        Qhp, Khp, Vtp, QSCALE);
    attn_mfma<true><<<gAtt, blk512, 0, stream>>>(Qhp, Khp, Vtp, attnb);
    gemm_bf16<2, 64, 64><<<g64, blk, 0, stream>>>(attnb, sa_woT, sa_bo, x, x1, nullptr, DD, DD);

    // ---- cross-attention block ----
    rmsnorm_kernel<<<MM, blk, 0, stream>>>(x1, g2, xnb);
    f2b_kernel<<<(MM * DD / 4) / 256, blk, 0, stream>>>(enc, encb);
    gemm_bf16<0, 128, 128><<<gKV, blk, 0, stream>>>(encb, ca_kvT, ca_bkv, nullptr, nullptr, kvb, DD, 2048);
    gemm_bf16<0, 64, 64><<<g64, blk, 0, stream>>>(xnb, ca_wqT, ca_bq, nullptr, nullptr, qn, DD, DD);
    qkv_prep<<<gPrep, blk, 0, stream>>>(qn, 1024, kvb, 2048, kvb + 1024, 2048,
                                        Qhp, Khp, Vtp, QSCALE);
    attn_mfma<false><<<gAtt, blk512, 0, stream>>>(Qhp, Khp, Vtp, attnb);
    gemm_bf16<2, 64, 64><<<g64, blk, 0, stream>>>(attnb, ca_woT, ca_bo, x1, x1, nullptr, DD, DD);

    // ---- FFN block ----
    rmsnorm_kernel<<<MM, blk, 0, stream>>>(x1, g3, xnb);
    gemm8w_bf16<1><<<gF1, blk512, 0, stream>>>(xnb, w1T, ff_b1, hb, DD, FFF);
    gemm_bf16<2, 64, 64><<<g64, blk, 0, stream>>>(hb, w2T, ff_b2, x1, out, nullptr, FFF, DD);
}

// Round 19
// 343.073 us; speedup vs baseline: 1.0124x; 1.0124x over previous
//
#include <hip/hip_runtime.h>
#include <hip/hip_bf16.h>
#include <math.h>

#define SS 1024
#define BB 4
#define DD 1024
#define HH 16
#define FFF 4096
#define MM (SS*BB)   // 4096 token rows

typedef __attribute__((ext_vector_type(8))) short bf16x8;
typedef __attribute__((ext_vector_type(4))) float f32x4;

#define VM_WAIT(n) asm volatile("s_waitcnt vmcnt(" #n ")" ::: "memory")
#define MEM_FENCE() asm volatile("" ::: "memory")

// ---------------- RMSNorm (fp32 in): one block per row, bf16 out ----------------
__global__ void rmsnorm_kernel(const float* __restrict__ x, const float* __restrict__ g,
                               __hip_bfloat16* __restrict__ out) {
    int row = blockIdx.x;
    const float* xr = x + (size_t)row * DD;
    int tid = threadIdx.x;
    float4 v = *reinterpret_cast<const float4*>(xr + tid * 4);
    float ss = v.x*v.x + v.y*v.y + v.z*v.z + v.w*v.w;
    #pragma unroll
    for (int off = 32; off; off >>= 1) ss += __shfl_down(ss, off);
    __shared__ float part[4];
    if ((tid & 63) == 0) part[tid >> 6] = ss;
    __syncthreads();
    float tot = part[0] + part[1] + part[2] + part[3];
    float rms = sqrtf(tot) * (1.0f / 32.0f);
    float inv = 1.0f / (rms + 1e-8f);
    float4 gv = *reinterpret_cast<const float4*>(g + tid * 4);
    union { __hip_bfloat16 h[4]; uint2 u; } p;
    p.h[0] = __float2bfloat16(gv.x * v.x * inv);
    p.h[1] = __float2bfloat16(gv.y * v.y * inv);
    p.h[2] = __float2bfloat16(gv.z * v.z * inv);
    p.h[3] = __float2bfloat16(gv.w * v.w * inv);
    reinterpret_cast<uint2*>(out + (size_t)row * DD)[tid] = p.u;
}

// ---------------- RMSNorm (bf16 in): one block per row, bf16 out ----------------
__global__ void rmsnormb_kernel(const __hip_bfloat16* __restrict__ x, const float* __restrict__ g,
                                __hip_bfloat16* __restrict__ out) {
    int row = blockIdx.x;
    int tid = threadIdx.x;
    union { uint2 u; __hip_bfloat16 h[4]; } d;
    d.u = reinterpret_cast<const uint2*>(x + (size_t)row * DD)[tid];
    float v0 = __bfloat162float(d.h[0]), v1 = __bfloat162float(d.h[1]);
    float v2 = __bfloat162float(d.h[2]), v3 = __bfloat162float(d.h[3]);
    float ss = v0*v0 + v1*v1 + v2*v2 + v3*v3;
    #pragma unroll
    for (int off = 32; off; off >>= 1) ss += __shfl_down(ss, off);
    __shared__ float part[4];
    if ((tid & 63) == 0) part[tid >> 6] = ss;
    __syncthreads();
    float tot = part[0] + part[1] + part[2] + part[3];
    float rms = sqrtf(tot) * (1.0f / 32.0f);
    float inv = 1.0f / (rms + 1e-8f);
    float4 gv = *reinterpret_cast<const float4*>(g + tid * 4);
    union { __hip_bfloat16 h[4]; uint2 u; } p;
    p.h[0] = __float2bfloat16(gv.x * v0 * inv);
    p.h[1] = __float2bfloat16(gv.y * v1 * inv);
    p.h[2] = __float2bfloat16(gv.z * v2 * inv);
    p.h[3] = __float2bfloat16(gv.w * v3 * inv);
    reinterpret_cast<uint2*>(out + (size_t)row * DD)[tid] = p.u;
}

// ---------------- fp32 -> bf16 elementwise ----------------
__global__ void f2b_kernel(const float* __restrict__ in, __hip_bfloat16* __restrict__ out) {
    int i = blockIdx.x * 256 + threadIdx.x;
    float4 v = reinterpret_cast<const float4*>(in)[i];
    union { __hip_bfloat16 h[4]; uint2 u; } p;
    p.h[0] = __float2bfloat16(v.x);
    p.h[1] = __float2bfloat16(v.y);
    p.h[2] = __float2bfloat16(v.z);
    p.h[3] = __float2bfloat16(v.w);
    reinterpret_cast<uint2*>(out)[i] = p.u;
}

// ---------------- bias concat (2 or 3 segments of n floats) ----------------
__global__ void bias_concat(const float* __restrict__ a, const float* __restrict__ b,
                            const float* __restrict__ c, float* __restrict__ o, int n) {
    int total = (c ? 3 : 2) * n;
    int i = blockIdx.x * 256 + threadIdx.x;
    if (i >= total) return;
    int seg = i / n, off = i - seg * n;
    const float* p = seg == 0 ? a : (seg == 1 ? b : c);
    o[i] = p[off];
}

// ---------------- batched transpose-convert: 8x W[1024,1024] fp32 -> Wt bf16 ----------------
__global__ void wtrans8_kernel(const float* s0, const float* s1, const float* s2, const float* s3,
                               const float* s4, const float* s5, const float* s6, const float* s7,
                               __hip_bfloat16* d0, __hip_bfloat16* d1, __hip_bfloat16* d2,
                               __hip_bfloat16* d3, __hip_bfloat16* d4, __hip_bfloat16* d5,
                               __hip_bfloat16* d6, __hip_bfloat16* d7) {
    const float* W; __hip_bfloat16* Wt;
    switch (blockIdx.z) {
        case 0: W = s0; Wt = d0; break;
        case 1: W = s1; Wt = d1; break;
        case 2: W = s2; Wt = d2; break;
        case 3: W = s3; Wt = d3; break;
        case 4: W = s4; Wt = d4; break;
        case 5: W = s5; Wt = d5; break;
        case 6: W = s6; Wt = d6; break;
        default: W = s7; Wt = d7; break;
    }
    __shared__ float tile[32][33];
    int n0 = blockIdx.x * 32, k0 = blockIdx.y * 32;
    int tx = threadIdx.x & 31, ty = threadIdx.x >> 5;
    #pragma unroll
    for (int i = 0; i < 4; i++) {
        int kk = ty + i * 8;
        tile[kk][tx] = W[(size_t)(k0 + kk) * DD + n0 + tx];
    }
    __syncthreads();
    #pragma unroll
    for (int i = 0; i < 4; i++) {
        int nn = ty + i * 8;
        Wt[(size_t)(n0 + nn) * DD + k0 + tx] = __float2bfloat16(tile[tx][nn]);
    }
}

// ---------------- transpose-convert: W[K,N] fp32 -> Wt[N,K] bf16 ----------------
__global__ void wtrans_kernel(const float* __restrict__ W, __hip_bfloat16* __restrict__ Wt,
                              int K, int N) {
    __shared__ float tile[32][33];
    int n0 = blockIdx.x * 32, k0 = blockIdx.y * 32;
    int tx = threadIdx.x & 31, ty = threadIdx.x >> 5;
    #pragma unroll
    for (int i = 0; i < 4; i++) {
        int kk = ty + i * 8;
        tile[kk][tx] = W[(size_t)(k0 + kk) * N + n0 + tx];
    }
    __syncthreads();
    #pragma unroll
    for (int i = 0; i < 4; i++) {
        int nn = ty + i * 8;
        Wt[(size_t)(n0 + nn) * K + k0 + tx] = __float2bfloat16(tile[tx][nn]);
    }
}

// ---------------- bf16 MFMA GEMM (proven r10 kernel) ----------------
// EPI: 0 = bias -> bf16 ; 1 = bias+silu -> bf16 ;
//      3 = bias + res(fp32) -> bf16 ; 4 = bias + res(bf16) -> bf16 ;
//      5 = bias + res(bf16) -> fp32
template<int EPI, int BM, int BN>
__global__ __launch_bounds__(256) void gemm_bf16(
    const __hip_bfloat16* __restrict__ A, const __hip_bfloat16* __restrict__ Bt,
    const float* __restrict__ bias, const float* __restrict__ resf,
    const __hip_bfloat16* __restrict__ resb,
    float* __restrict__ Cf, __hip_bfloat16* __restrict__ Cb, int K, int N)
{
    constexpr int MFRAG = BM / 32;
    constexpr int NFRAG = BN / 32;
    constexpr int WM = BM / 2, WN = BN / 2;
    constexpr int LPT = (BM + BN) / 32;
    __shared__ __hip_bfloat16 As[2][BM * 64];
    __shared__ __hip_bfloat16 Bs[2][BN * 64];
    int tid = threadIdx.x;
    int lane = tid & 63, w = tid >> 6;
    int wr = w >> 1, wc = w & 1;

    int gx = gridDim.x;
    int nwg = gx * gridDim.y;
    int orig = blockIdx.y * gx + blockIdx.x;
    int qd = nwg >> 3, rr2 = nwg & 7, xcd = orig & 7, pos = orig >> 3;
    int lin = (xcd < rr2 ? xcd * (qd + 1) : rr2 * (qd + 1) + (xcd - rr2) * qd) + pos;
    int brow = (lin / gx) * BM, bcol = (lin % gx) * BN;

    f32x4 acc[MFRAG][NFRAG];
    #pragma unroll
    for (int m = 0; m < MFRAG; m++)
        #pragma unroll
        for (int n = 0; n < NFRAG; n++)
            acc[m][n] = (f32x4){0.f, 0.f, 0.f, 0.f};

    const __hip_bfloat16* Ab = A + (size_t)brow * K;
    const __hip_bfloat16* Bb = Bt + (size_t)bcol * K;

    auto stage = [&](int buf, int kt) {
        #pragma unroll
        for (int i = 0; i < BM / 32; i++) {
            int f = i * 256 + tid;
            int row = f >> 3, cp = f & 7;
            int cs = cp ^ (row & 7);
            __builtin_amdgcn_global_load_lds(
                (const __attribute__((address_space(1))) void*)(Ab + (size_t)row * K + kt + cs * 8),
                (__attribute__((address_space(3))) void*)(As[buf] + (size_t)(i * 256 + w * 64) * 8),
                16, 0, 0);
        }
        #pragma unroll
        for (int i = 0; i < BN / 32; i++) {
            int f = i * 256 + tid;
            int row = f >> 3, cp = f & 7;
            int cs = cp ^ (row & 7);
            __builtin_amdgcn_global_load_lds(
                (const __attribute__((address_space(1))) void*)(Bb + (size_t)row * K + kt + cs * 8),
                (__attribute__((address_space(3))) void*)(Bs[buf] + (size_t)(i * 256 + w * 64) * 8),
                16, 0, 0);
        }
    };

    int nt = K >> 6;
    stage(0, 0);
    if (nt > 1) stage(1, 64);

    int cb = 0;
    int r = lane & 15, g = lane >> 4;
    for (int t = 0; t < nt; t++) {
        if (t + 1 < nt) {
            if constexpr (LPT == 4) VM_WAIT(4); else VM_WAIT(8);
        } else VM_WAIT(0);
        __builtin_amdgcn_s_barrier();
        MEM_FENCE();

        bf16x8 aF[2][MFRAG], bF[2][NFRAG];
        #pragma unroll
        for (int kk = 0; kk < 2; kk++) {
            #pragma unroll
            for (int m = 0; m < MFRAG; m++) {
                int row = WM * wr + m * 16 + r;
                aF[kk][m] = *reinterpret_cast<const bf16x8*>(
                    As[cb] + (size_t)row * 64 + (size_t)((kk * 4 + g) ^ (row & 7)) * 8);
            }
            #pragma unroll
            for (int n = 0; n < NFRAG; n++) {
                int row = WN * wc + n * 16 + r;
                bF[kk][n] = *reinterpret_cast<const bf16x8*>(
                    Bs[cb] + (size_t)row * 64 + (size_t)((kk * 4 + g) ^ (row & 7)) * 8);
            }
        }
        __builtin_amdgcn_s_setprio(1);
        #pragma unroll
        for (int kk = 0; kk < 2; kk++)
            #pragma unroll
            for (int m = 0; m < MFRAG; m++)
                #pragma unroll
                for (int n = 0; n < NFRAG; n++)
                    acc[m][n] = __builtin_amdgcn_mfma_f32_16x16x32_bf16(aF[kk][m], bF[kk][n], acc[m][n], 0, 0, 0);
        __builtin_amdgcn_s_setprio(0);

        MEM_FENCE();
        __builtin_amdgcn_s_barrier();
        if (t + 2 < nt) stage(cb, (t + 2) << 6);
        cb ^= 1;
    }

    int row0 = brow + WM * wr + (g * 4);
    int col0 = bcol + WN * wc + r;
    #pragma unroll
    for (int m = 0; m < MFRAG; m++) {
        #pragma unroll
        for (int n = 0; n < NFRAG; n++) {
            int ccol = col0 + n * 16;
            float bv = bias[ccol];
            #pragma unroll
            for (int q = 0; q < 4; q++) {
                int rrow = row0 + m * 16 + q;
                float o = acc[m][n][q] + bv;
                if (EPI == 0) {
                    Cb[(size_t)rrow * N + ccol] = __float2bfloat16(o);
                } else if (EPI == 1) {
                    o = o / (1.0f + __expf(-o));
                    Cb[(size_t)rrow * N + ccol] = __float2bfloat16(o);
                } else if (EPI == 3) {
                    o += resf[(size_t)rrow * N + ccol];
                    Cb[(size_t)rrow * N + ccol] = __float2bfloat16(o);
                } else if (EPI == 4) {
                    o += __bfloat162float(resb[(size_t)rrow * N + ccol]);
                    Cb[(size_t)rrow * N + ccol] = __float2bfloat16(o);
                } else {
                    o += __bfloat162float(resb[(size_t)rrow * N + ccol]);
                    Cf[(size_t)rrow * N + ccol] = o;
                }
            }
        }
    }
}

// ---------------- 8-wave 256x256 GEMM (passing r18; FFN-up only) ----------------
template<int EPI>
__global__ __launch_bounds__(512) void gemm8w_bf16(
    const __hip_bfloat16* __restrict__ A, const __hip_bfloat16* __restrict__ Bt,
    const float* __restrict__ bias, __hip_bfloat16* __restrict__ Cb, int K, int N)
{
    constexpr int BM = 256, BN = 256;
    constexpr int MFRAG = 8, NFRAG = 4;
    __shared__ __hip_bfloat16 As[2][BM * 64];
    __shared__ __hip_bfloat16 Bs[2][BN * 64];
    int tid = threadIdx.x;
    int lane = tid & 63, w = tid >> 6;
    int wr = w >> 2, wc = w & 3;

    int gx = gridDim.x;
    int nwg = gx * gridDim.y;
    int orig = blockIdx.y * gx + blockIdx.x;
    int qd = nwg >> 3, rr2 = nwg & 7, xcd = orig & 7, pos = orig >> 3;
    int lin = (xcd < rr2 ? xcd * (qd + 1) : rr2 * (qd + 1) + (xcd - rr2) * qd) + pos;
    int brow = (lin / gx) * BM, bcol = (lin % gx) * BN;

    f32x4 acc[MFRAG][NFRAG];
    #pragma unroll
    for (int m = 0; m < MFRAG; m++)
        #pragma unroll
        for (int n = 0; n < NFRAG; n++)
            acc[m][n] = (f32x4){0.f, 0.f, 0.f, 0.f};

    const __hip_bfloat16* Ab = A + (size_t)brow * K;
    const __hip_bfloat16* Bb = Bt + (size_t)bcol * K;

    auto stage = [&](int buf, int kt) {
        #pragma unroll
        for (int i = 0; i < 4; i++) {
            int f = i * 512 + tid;
            int row = f >> 3, cp = f & 7;
            int cs = cp ^ (row & 7);
            __builtin_amdgcn_global_load_lds(
                (const __attribute__((address_space(1))) void*)(Ab + (size_t)row * K + kt + cs * 8),
                (__attribute__((address_space(3))) void*)(As[buf] + (size_t)(i * 512 + w * 64) * 8),
                16, 0, 0);
        }
        #pragma unroll
        for (int i = 0; i < 4; i++) {
            int f = i * 512 + tid;
            int row = f >> 3, cp = f & 7;
            int cs = cp ^ (row & 7);
            __builtin_amdgcn_global_load_lds(
                (const __attribute__((address_space(1))) void*)(Bb + (size_t)row * K + kt + cs * 8),
                (__attribute__((address_space(3))) void*)(Bs[buf] + (size_t)(i * 512 + w * 64) * 8),
                16, 0, 0);
        }
    };

    int nt = K >> 6;
    stage(0, 0);
    if (nt > 1) stage(1, 64);

    int cb = 0;
    int r = lane & 15, g = lane >> 4;
    for (int t = 0; t < nt; t++) {
        if (t + 1 < nt) VM_WAIT(8); else VM_WAIT(0);
        __builtin_amdgcn_s_barrier();
        MEM_FENCE();

        #pragma unroll
        for (int kk = 0; kk < 2; kk++) {
            bf16x8 aF[MFRAG], bF[NFRAG];
            #pragma unroll
            for (int m = 0; m < MFRAG; m++) {
                int row = 128 * wr + m * 16 + r;
                aF[m] = *reinterpret_cast<const bf16x8*>(
                    As[cb] + (size_t)row * 64 + (size_t)((kk * 4 + g) ^ (row & 7)) * 8);
            }
            #pragma unroll
            for (int n = 0; n < NFRAG; n++) {
                int row = 64 * wc + n * 16 + r;
                bF[n] = *reinterpret_cast<const bf16x8*>(
                    Bs[cb] + (size_t)row * 64 + (size_t)((kk * 4 + g) ^ (row & 7)) * 8);
            }
            __builtin_amdgcn_s_setprio(1);
            #pragma unroll
            for (int m = 0; m < MFRAG; m++)
                #pragma unroll
                for (int n = 0; n < NFRAG; n++)
                    acc[m][n] = __builtin_amdgcn_mfma_f32_16x16x32_bf16(aF[m], bF[n], acc[m][n], 0, 0, 0);
            __builtin_amdgcn_s_setprio(0);
        }

        MEM_FENCE();
        __builtin_amdgcn_s_barrier();
        if (t + 2 < nt) stage(cb, (t + 2) << 6);
        cb ^= 1;
    }

    int row0 = brow + 128 * wr + (g * 4);
    int col0 = bcol + 64 * wc + r;
    #pragma unroll
    for (int m = 0; m < MFRAG; m++) {
        #pragma unroll
        for (int n = 0; n < NFRAG; n++) {
            int ccol = col0 + n * 16;
            float bv = bias[ccol];
            #pragma unroll
            for (int q = 0; q < 4; q++) {
                int rrow = row0 + m * 16 + q;
                float o = acc[m][n][q] + bv;
                if (EPI == 1) o = o / (1.0f + __expf(-o));
                Cb[(size_t)rrow * N + ccol] = __float2bfloat16(o);
            }
        }
    }
}

// ---------------- fused Q/K RoPE + relayout + V transpose (unchanged, passing) ----------------
__global__ __launch_bounds__(256) void qkv_prep(
    const __hip_bfloat16* __restrict__ Q, int qs,
    const __hip_bfloat16* __restrict__ K, int ks2,
    const __hip_bfloat16* __restrict__ V, int vs,
    __hip_bfloat16* __restrict__ Qh, __hip_bfloat16* __restrict__ Kh,
    __hip_bfloat16* __restrict__ Vt, float qscale)
{
    int tid = threadIdx.x;
    int bh = blockIdx.y;
    int b = bh >> 4, h = bh & 15;
    int s0 = blockIdx.x * 64;
    #pragma unroll
    for (int sel = 0; sel < 2; sel++) {
        const __hip_bfloat16* src = sel ? K : Q;
        int stride = sel ? ks2 : qs;
        __hip_bfloat16* dst = sel ? Kh : Qh;
        float sc = sel ? 1.0f : qscale;
        #pragma unroll
        for (int it = 0; it < 2; it++) {
            int f = it * 256 + tid;
            int i = f >> 3, c8 = f & 7;
            int s = s0 + i;
            union { uint4 u; __hip_bfloat16 hh[8]; } d;
            d.u = *reinterpret_cast<const uint4*>(src + (size_t)(s * BB + b) * stride + h * 64 + c8 * 8);
            float fv[8];
            #pragma unroll
            for (int e = 0; e < 8; e++) fv[e] = __bfloat162float(d.hh[e]);
            if (c8 < 4) {
                #pragma unroll
                for (int pp = 0; pp < 4; pp++) {
                    int p = c8 * 4 + pp;
                    float ang = (float)s * __powf(10000.f, -(float)p * (1.0f / 16.0f));
                    float cc, sn;
                    __sincosf(ang, &sn, &cc);
                    float x0 = fv[pp * 2], x1 = fv[pp * 2 + 1];
                    fv[pp * 2]     = x0 * cc - x1 * sn;
                    fv[pp * 2 + 1] = x1 * cc + x0 * sn;
                }
            }
            #pragma unroll
            for (int e = 0; e < 8; e++) d.hh[e] = __float2bfloat16(fv[e] * sc);
            *reinterpret_cast<uint4*>(dst + ((size_t)bh * SS + s) * 64 + c8 * 8) = d.u;
        }
    }
    __shared__ __hip_bfloat16 t[64][72];
    #pragma unroll
    for (int i = 0; i < 2; i++) {
        int f = tid + i * 256;
        int sr = f >> 3, c = (f & 7) * 8;
        *reinterpret_cast<uint4*>(&t[sr][c]) =
            *reinterpret_cast<const uint4*>(V + (size_t)((s0 + sr) * BB + b) * vs + h * 64 + c);
    }
    __syncthreads();
    #pragma unroll
    for (int i = 0; i < 2; i++) {
        int f = tid + i * 256;
        int d = f >> 3, c = (f & 7) * 8;
        __hip_bfloat16 tmp[8];
        #pragma unroll
        for (int j = 0; j < 8; j++) tmp[j] = t[c + j][d];
        *reinterpret_cast<uint4*>(Vt + ((size_t)bh * 64 + d) * SS + s0 + c) =
            *reinterpret_cast<uint4*>(tmp);
    }
}

// ---------------- MFMA flash attention (unchanged from r15/r18, passing) ----------------
template<bool CAUSAL>
__global__ __launch_bounds__(512) void attn_mfma(
    const __hip_bfloat16* __restrict__ Qh, const __hip_bfloat16* __restrict__ Kh,
    const __hip_bfloat16* __restrict__ Vth, __hip_bfloat16* __restrict__ O)
{
    __shared__ __hip_bfloat16 Ks[2][64 * 64];
    __shared__ __hip_bfloat16 Vs[2][64 * 64];
    __shared__ __hip_bfloat16 Ps[8][16][72];
    int tid = threadIdx.x, lane = tid & 63, w = tid >> 6;
    int r = lane & 15, g = lane >> 4;

    int lin = blockIdx.y * gridDim.x + blockIdx.x;
    int bh = (lin & 7) * 8 + ((lin >> 3) & 7);
    int qblk = lin >> 6;
    int b = bh >> 4, h = bh & 15;
    int qb = qblk * 128;
    const __hip_bfloat16* gQ = Qh + (size_t)bh * SS * 64;
    const __hip_bfloat16* gK = Kh + (size_t)bh * SS * 64;
    const __hip_bfloat16* gV = Vth + (size_t)bh * 64 * SS;

    bf16x8 qf0 = *reinterpret_cast<const bf16x8*>(gQ + (size_t)(qb + w * 16 + r) * 64 + g * 8);
    bf16x8 qf1 = *reinterpret_cast<const bf16x8*>(gQ + (size_t)(qb + w * 16 + r) * 64 + 32 + g * 8);

    const short oneb = (short)0x3F80;
    bf16x8 onesV = {oneb, oneb, oneb, oneb, oneb, oneb, oneb, oneb};

    f32x4 accO[4];
    f32x4 accL = (f32x4){0.f, 0.f, 0.f, 0.f};
    #pragma unroll
    for (int j = 0; j < 4; j++) accO[j] = (f32x4){0.f, 0.f, 0.f, 0.f};

    int nt = CAUSAL ? 2 * (qblk + 1) : (SS / 64);

    auto stage = [&](int buf, int kt) {
        int row = tid >> 3, cp = tid & 7;
        int cs = cp ^ (row & 7);
        __builtin_amdgcn_global_load_lds(
            (const __attribute__((address_space(1))) void*)(gK + (size_t)(kt + row) * 64 + cs * 8),
            (__attribute__((address_space(3))) void*)(&Ks[buf][(size_t)tid * 8]),
            16, 0, 0);
        __builtin_amdgcn_global_load_lds(
            (const __attribute__((address_space(1))) void*)(gV + (size_t)row * SS + kt + cs * 8),
            (__attribute__((address_space(3))) void*)(&Vs[buf][(size_t)tid * 8]),
            16, 0, 0);
    };

    stage(0, 0);
    if (nt > 1) stage(1, 64);
    int cb = 0;
    for (int t = 0; t < nt; t++) {
        if (t + 1 < nt) VM_WAIT(2); else VM_WAIT(0);
        __builtin_amdgcn_s_barrier();
        MEM_FENCE();
        int kt = t * 64;

        f32x4 sa[4];
        __builtin_amdgcn_s_setprio(1);
        #pragma unroll
        for (int ks = 0; ks < 4; ks++) {
            sa[ks] = (f32x4){0.f, 0.f, 0.f, 0.f};
            int rk = ks * 16 + r;
            bf16x8 kf0 = *reinterpret_cast<const bf16x8*>(&Ks[cb][rk * 64 + ((g ^ (rk & 7)) * 8)]);
            bf16x8 kf1 = *reinterpret_cast<const bf16x8*>(&Ks[cb][rk * 64 + (((4 + g) ^ (rk & 7)) * 8)]);
            sa[ks] = __builtin_amdgcn_mfma_f32_16x16x32_bf16(qf0, kf0, sa[ks], 0, 0, 0);
            sa[ks] = __builtin_amdgcn_mfma_f32_16x16x32_bf16(qf1, kf1, sa[ks], 0, 0, 0);
        }
        __builtin_amdgcn_s_setprio(0);

        if (CAUSAL && t >= nt - 2) {
            #pragma unroll
            for (int ks = 0; ks < 4; ks++) {
                int key = kt + ks * 16 + r;
                #pragma unroll
                for (int j = 0; j < 4; j++) {
                    int qq = qb + w * 16 + g * 4 + j;
                    if (key > qq) sa[ks][j] = -1e9f;
                }
            }
        }

        #pragma unroll
        for (int ks = 0; ks < 4; ks++)
            #pragma unroll
            for (int j = 0; j < 4; j++)
                Ps[w][g * 4 + j][ks * 16 + r] = __float2bfloat16(exp2f(sa[ks][j]));

        __builtin_amdgcn_s_setprio(1);
        #pragma unroll
        for (int ks2 = 0; ks2 < 2; ks2++) {
            bf16x8 pf = *reinterpret_cast<const bf16x8*>(&Ps[w][r][ks2 * 32 + g * 8]);
            accL = __builtin_amdgcn_mfma_f32_16x16x32_bf16(pf, onesV, accL, 0, 0, 0);
            #pragma unroll
            for (int ds = 0; ds < 4; ds++) {
                int rv = ds * 16 + r;
                bf16x8 vf = *reinterpret_cast<const bf16x8*>(
                    &Vs[cb][rv * 64 + (((ks2 * 4 + g) ^ (rv & 7)) * 8)]);
                accO[ds] = __builtin_amdgcn_mfma_f32_16x16x32_bf16(pf, vf, accO[ds], 0, 0, 0);
            }
        }
        __builtin_amdgcn_s_setprio(0);

        MEM_FENCE();
        __builtin_amdgcn_s_barrier();
        if (t + 2 < nt) stage(cb, (t + 2) * 64);
        cb ^= 1;
    }

    #pragma unroll
    for (int j = 0; j < 4; j++) {
        float inv = 1.0f / accL[j];
        int s = qb + w * 16 + g * 4 + j;
        #pragma unroll
        for (int ds = 0; ds < 4; ds++)
            O[(size_t)(s * BB + b) * DD + h * 64 + ds * 16 + r] =
                __float2bfloat16(accO[ds][j] * inv);
    }
}

extern "C" void kernel_launch(void* const* d_in, const int* in_sizes, int n_in,
                              void* d_out, int out_size, void* d_ws, size_t ws_size,
                              hipStream_t stream) {
    const float* x    = (const float*)d_in[0];
    const float* enc  = (const float*)d_in[1];
    const float* sa_wq = (const float*)d_in[3];
    const float* sa_bq = (const float*)d_in[4];
    const float* sa_wk = (const float*)d_in[5];
    const float* sa_bk = (const float*)d_in[6];
    const float* sa_wv = (const float*)d_in[7];
    const float* sa_bv = (const float*)d_in[8];
    const float* sa_wo = (const float*)d_in[9];
    const float* sa_bo = (const float*)d_in[10];
    const float* ca_wq = (const float*)d_in[11];
    const float* ca_bq = (const float*)d_in[12];
    const float* ca_wk = (const float*)d_in[13];
    const float* ca_bk = (const float*)d_in[14];
    const float* ca_wv = (const float*)d_in[15];
    const float* ca_bv = (const float*)d_in[16];
    const float* ca_wo = (const float*)d_in[17];
    const float* ca_bo = (const float*)d_in[18];
    const float* ff_w1 = (const float*)d_in[19];
    const float* ff_b1 = (const float*)d_in[20];
    const float* ff_w2 = (const float*)d_in[21];
    const float* ff_b2 = (const float*)d_in[22];
    const float* g1 = (const float*)d_in[23];
    const float* g2 = (const float*)d_in[24];
    const float* g3 = (const float*)d_in[25];
    float* out = (float*)d_out;

    // ---- workspace map (112 MB) ----
    const size_t MB = 1024 * 1024;
    char* base = (char*)d_ws;
    __hip_bfloat16* sa_qkvT = (__hip_bfloat16*)(base + 0 * MB);   // [3072][1024] 6MB
    __hip_bfloat16* sa_woT  = (__hip_bfloat16*)(base + 6 * MB);   // 2MB
    __hip_bfloat16* ca_wqT  = (__hip_bfloat16*)(base + 8 * MB);   // 2MB
    __hip_bfloat16* ca_kvT  = (__hip_bfloat16*)(base + 10 * MB);  // [2048][1024] 4MB
    __hip_bfloat16* ca_woT  = (__hip_bfloat16*)(base + 14 * MB);  // 2MB
    __hip_bfloat16* w1T     = (__hip_bfloat16*)(base + 16 * MB);  // [FFF][DD] 8MB
    __hip_bfloat16* w2T     = (__hip_bfloat16*)(base + 24 * MB);  // [DD][FFF] 8MB
    float* sa_bqkv = (float*)(base + 32 * MB);                    // 3072 f
    float* ca_bkv  = (float*)(base + 32 * MB + 16384);            // 2048 f
    __hip_bfloat16* xnb   = (__hip_bfloat16*)(base + 33 * MB);    // 8MB (also attnb)
    __hip_bfloat16* qkv   = (__hip_bfloat16*)(base + 41 * MB);    // [M][3072] 24MB
    __hip_bfloat16* Qhp   = (__hip_bfloat16*)(base + 65 * MB);    // 8MB (also encb)
    __hip_bfloat16* Khp   = (__hip_bfloat16*)(base + 73 * MB);    // 8MB
    __hip_bfloat16* Vtp   = (__hip_bfloat16*)(base + 81 * MB);    // 8MB
    __hip_bfloat16* x1b   = (__hip_bfloat16*)(base + 96 * MB);    // 8MB (bf16 residual)
    __hip_bfloat16* x2b   = (__hip_bfloat16*)(base + 104 * MB);   // 8MB (bf16 residual)
    __hip_bfloat16* attnb = xnb;
    __hip_bfloat16* encb  = Qhp;
    __hip_bfloat16* qn    = qkv;                                  // CA: [M][1024] 8MB
    __hip_bfloat16* kvb   = qkv + (size_t)4 * MB;                 // CA: [M][2048] 16MB
    __hip_bfloat16* hb    = qkv;                                  // FFN: [M][FFF] 32MB (41..73)

    const float QSCALE = 0.125f * 1.44269504089f;  // 1/sqrt(64) * log2(e)

    dim3 blk(256);
    dim3 blk512(512);
    dim3 gT8(32, 32, 8);
    dim3 gW1(FFF / 32, DD / 32);
    dim3 gW2(DD / 32, FFF / 32);
    dim3 gQKV(3072 / 128, MM / 128);    // 768 blocks (proven 128^2)
    dim3 gKV(2048 / 128, MM / 128);     // 512 blocks (proven 128^2)
    dim3 gF1(FFF / 256, MM / 256);      // 256 blocks (8-wave 256^2)
    dim3 g64(DD / 64, MM / 64);         // 1024 blocks
    dim3 gPrep(SS / 64, BB * HH);
    dim3 gAtt(SS / 128, BB * HH);       // 512 blocks, 512 thr each

    // ---- one-time conversions ----
    wtrans8_kernel<<<gT8, blk, 0, stream>>>(
        sa_wq, sa_wk, sa_wv, sa_wo, ca_wq, ca_wk, ca_wv, ca_wo,
        sa_qkvT, sa_qkvT + (size_t)1024 * DD, sa_qkvT + (size_t)2048 * DD, sa_woT,
        ca_wqT, ca_kvT, ca_kvT + (size_t)1024 * DD, ca_woT);
    wtrans_kernel<<<gW1, blk, 0, stream>>>(ff_w1, w1T, DD, FFF);
    wtrans_kernel<<<gW2, blk, 0, stream>>>(ff_w2, w2T, FFF, DD);
    bias_concat<<<12, blk, 0, stream>>>(sa_bq, sa_bk, sa_bv, sa_bqkv, DD);
    bias_concat<<<8, blk, 0, stream>>>(ca_bk, ca_bv, nullptr, ca_bkv, DD);

    // ---- self-attention block ----
    rmsnorm_kernel<<<MM, blk, 0, stream>>>(x, g1, xnb);
    gemm_bf16<0, 128, 128><<<gQKV, blk, 0, stream>>>(xnb, sa_qkvT, sa_bqkv, nullptr, nullptr, nullptr, qkv, DD, 3072);
    qkv_prep<<<gPrep, blk, 0, stream>>>(qkv, 3072, qkv + 1024, 3072, qkv + 2048, 3072,
                                        Qhp, Khp, Vtp, QSCALE);
    attn_mfma<true><<<gAtt, blk512, 0, stream>>>(Qhp, Khp, Vtp, attnb);
    gemm_bf16<3, 64, 64><<<g64, blk, 0, stream>>>(attnb, sa_woT, sa_bo, x, nullptr, nullptr, x1b, DD, DD);

    // ---- cross-attention block ----
    rmsnormb_kernel<<<MM, blk, 0, stream>>>(x1b, g2, xnb);
    f2b_kernel<<<(MM * DD / 4) / 256, blk, 0, stream>>>(enc, encb);
    gemm_bf16<0, 128, 128><<<gKV, blk, 0, stream>>>(encb, ca_kvT, ca_bkv, nullptr, nullptr, nullptr, kvb, DD, 2048);
    gemm_bf16<0, 64, 64><<<g64, blk, 0, stream>>>(xnb, ca_wqT, ca_bq, nullptr, nullptr, nullptr, qn, DD, DD);
    qkv_prep<<<gPrep, blk, 0, stream>>>(qn, 1024, kvb, 2048, kvb + 1024, 2048,
                                        Qhp, Khp, Vtp, QSCALE);
    attn_mfma<false><<<gAtt, blk512, 0, stream>>>(Qhp, Khp, Vtp, attnb);
    gemm_bf16<4, 64, 64><<<g64, blk, 0, stream>>>(attnb, ca_woT, ca_bo, nullptr, x1b, nullptr, x2b, DD, DD);

    // ---- FFN block ----
    rmsnormb_kernel<<<MM, blk, 0, stream>>>(x2b, g3, xnb);
    gemm8w_bf16<1><<<gF1, blk512, 0, stream>>>(xnb, w1T, ff_b1, hb, DD, FFF);
    gemm_bf16<5, 64, 64><<<g64, blk, 0, stream>>>(hb, w2T, ff_b2, nullptr, x2b, out, nullptr, FFF, DD);
}